// Round 12
// baseline (314.699 us; speedup 1.0000x reference)
//
#include <hip/hip_runtime.h>
#include <hip/hip_bf16.h>
#include <math.h>

// Problem constants
#define Bb   256
#define Nn   400
#define FIN  400
#define Hh   64
#define NNZ  16000
#define Mrows (Bb*Nn)          // 102400
#define KP   416               // dense-adj K padded to 13*32 for MFMA
#define UPAD 420               // fused-kernel LDS node stride (shorts)
#define BH_COUNT 16384.0f      // B*H for BN3 stats

typedef unsigned int  u32x2 __attribute__((ext_vector_type(2)));
typedef unsigned int  u32x4 __attribute__((ext_vector_type(4)));
typedef __bf16        bf16x8 __attribute__((ext_vector_type(8)));
typedef float         f32x4 __attribute__((ext_vector_type(4)));

__device__ __forceinline__ unsigned int f2bf(float x) {
    unsigned int u = __builtin_bit_cast(unsigned int, x);
    return (u + 0x7FFFu + ((u >> 16) & 1u)) >> 16;   // RNE
}
__device__ __forceinline__ float bf2f(unsigned int h) {
    unsigned int u = h << 16;
    return __builtin_bit_cast(float, u);
}

// ---------------------------------------------------------------------------
// init: zero dense-A f32 accumulator + BN stats
// ---------------------------------------------------------------------------
__global__ void initk(float* __restrict__ Adf, float* __restrict__ stats) {
    int t = blockIdx.x * blockDim.x + threadIdx.x;
    if (t < Nn * KP) Adf[t] = 0.f;
    if (t < 1600) stats[t] = 0.f;   // ssum1, ssq1, ssum2, ssq2 (4 x 400)
}

__global__ void scatAk(const int* __restrict__ rows, const int* __restrict__ cols,
                       const float* __restrict__ vals, float* __restrict__ Adf) {
    int i = blockIdx.x * blockDim.x + threadIdx.x;
    if (i < NNZ) atomicAdd(&Adf[rows[i] * KP + cols[i]], vals[i]);
}

__global__ void cvtAk(const float* __restrict__ Adf, unsigned short* __restrict__ Adbf) {
    int i = blockIdx.x * blockDim.x + threadIdx.x;
    if (i < Nn * KP) Adbf[i] = (unsigned short)f2bf(Adf[i]);
}

// ---------------------------------------------------------------------------
// W prep: split W[KT][64] -> hi/lo bf16 in B-fragment layout [col][KPAD]
// ---------------------------------------------------------------------------
__global__ __launch_bounds__(256) void wprep(
        const float* __restrict__ W1, const float* __restrict__ W2,
        const float* __restrict__ W3,
        unsigned short* __restrict__ T1h, unsigned short* __restrict__ T1l,
        unsigned short* __restrict__ T2h, unsigned short* __restrict__ T2l,
        unsigned short* __restrict__ T3h, unsigned short* __restrict__ T3l) {
    const int w = blockIdx.x >> 6;        // 0,1,2
    const int c = blockIdx.x & 63;
    const float* W = (w == 0) ? W1 : (w == 1) ? W2 : W3;
    const int KT   = (w == 0) ? FIN : Hh;
    const int KPAD = (w == 0) ? 416 : 64;
    unsigned short* Th = (w == 0) ? T1h : (w == 1) ? T2h : T3h;
    unsigned short* Tl = (w == 0) ? T1l : (w == 1) ? T2l : T3l;

    for (int k = threadIdx.x; k < KPAD; k += 256) {
        float v = (k < KT) ? W[k * 64 + c] : 0.f;
        unsigned int hb = f2bf(v);
        Th[c * KPAD + k] = (unsigned short)hb;
        Tl[c * KPAD + k] = (unsigned short)f2bf(v - bf2f(hb));
    }
}

// ---------------------------------------------------------------------------
// Fused layer 1: block = ONE BATCH (grid 256, 1024 thr = 16 waves).
// Phase A (2 tiles/wave t=wv, wv+16; pipelined 13 K-steps):
//   U[b] = x[b,400x400](f32) @ W1 (split-precision MFMA) -> LDS Us (bf16)
// sync
// Phase B (single K sweep, 2 live tiles):
//   Z1[b] = relu(normalize(Adj @ U[b] + b1)) + BN stat atomics
// Per-element arithmetic identical to R11's xg400+aggmm path.
// ---------------------------------------------------------------------------
__global__ __launch_bounds__(1024) void fused1(
        const float* __restrict__ x,
        const unsigned short* __restrict__ Wth,   // [64][416] frag layout
        const unsigned short* __restrict__ Wtl,
        const unsigned short* __restrict__ Ad,    // [400][416] bf16 bits
        const float* __restrict__ bias,
        float* __restrict__ Zout,
        float* __restrict__ ssum, float* __restrict__ ssq) {
    __shared__ unsigned short Us[64 * UPAD];      // 53760 B
    const int b    = blockIdx.x;
    const int tid  = threadIdx.x;
    const int wv   = tid >> 6;                    // 0..15
    const int lane = tid & 63;
    const int cl   = lane & 15;
    const int g    = lane >> 4;

    // zero LDS pad rows (node 400..419)
    for (int i = tid; i < 64 * (UPAD - Nn); i += 1024) {
        int c = i / (UPAD - Nn), k = Nn + i % (UPAD - Nn);
        Us[c * UPAD + k] = 0;
    }

    // ---- Phase A: x[b] @ W1 -> LDS (split precision, pipelined) ----
    const int t0 = wv, t1 = wv + 16;
    const bool has1 = (t1 < 25);
    const int r0 = t0 * 16 + cl;
    const int r1 = has1 ? (t1 * 16 + cl) : r0;
    const float* __restrict__ A0 = &x[((size_t)b * Nn + r0) * FIN];
    const float* __restrict__ A1 = &x[((size_t)b * Nn + r1) * FIN];

    f32x4 acc[2][4];
#pragma unroll
    for (int t2 = 0; t2 < 2; ++t2)
#pragma unroll
        for (int n = 0; n < 4; ++n) acc[t2][n] = f32x4{0.f, 0.f, 0.f, 0.f};

    auto loadA = [&](int s, float4& l0, float4& h0, float4& l1, float4& h1) {
        int kk = s * 32 + g * 8;
        int kc = kk > 392 ? 392 : kk;                 // clamp (W pad is zero)
        l0 = *reinterpret_cast<const float4*>(A0 + kc);
        h0 = *reinterpret_cast<const float4*>(A0 + kc + 4);
        l1 = *reinterpret_cast<const float4*>(A1 + kc);
        h1 = *reinterpret_cast<const float4*>(A1 + kc + 4);
    };
    auto loadW = [&](int s, u32x4* dst) {
        int kk = s * 32 + g * 8;
#pragma unroll
        for (int n = 0; n < 4; ++n) {
            dst[n]     = *reinterpret_cast<const u32x4*>(&Wth[(size_t)(n * 16 + cl) * 416 + kk]);
            dst[4 + n] = *reinterpret_cast<const u32x4*>(&Wtl[(size_t)(n * 16 + cl) * 416 + kk]);
        }
    };
    auto split = [&](const float4& lo, const float4& hi, bf16x8& ah, bf16x8& al) {
        float v0 = lo.x, v1 = lo.y, v2 = lo.z, v3 = lo.w;
        float v4 = hi.x, v5 = hi.y, v6 = hi.z, v7 = hi.w;
        unsigned h0, h1;
        u32x4 hw, lw;
        h0 = f2bf(v0); h1 = f2bf(v1);
        hw[0] = h0 | (h1 << 16);
        lw[0] = f2bf(v0 - bf2f(h0)) | (f2bf(v1 - bf2f(h1)) << 16);
        h0 = f2bf(v2); h1 = f2bf(v3);
        hw[1] = h0 | (h1 << 16);
        lw[1] = f2bf(v2 - bf2f(h0)) | (f2bf(v3 - bf2f(h1)) << 16);
        h0 = f2bf(v4); h1 = f2bf(v5);
        hw[2] = h0 | (h1 << 16);
        lw[2] = f2bf(v4 - bf2f(h0)) | (f2bf(v5 - bf2f(h1)) << 16);
        h0 = f2bf(v6); h1 = f2bf(v7);
        hw[3] = h0 | (h1 << 16);
        lw[3] = f2bf(v6 - bf2f(h0)) | (f2bf(v7 - bf2f(h1)) << 16);
        ah = __builtin_bit_cast(bf16x8, hw);
        al = __builtin_bit_cast(bf16x8, lw);
    };

    float4 cAl0, cAh0, cAl1, cAh1, nAl0, nAh0, nAl1, nAh1;
    u32x4  cW[8], nW[8];
    loadA(0, cAl0, cAh0, cAl1, cAh1);
    loadW(0, cW);

    for (int s = 0; s < 13; ++s) {
        if (s < 12) {
            loadA(s + 1, nAl0, nAh0, nAl1, nAh1);
            loadW(s + 1, nW);
        }
        bf16x8 ah0, al0, ah1, al1;
        split(cAl0, cAh0, ah0, al0);
        split(cAl1, cAh1, ah1, al1);
#pragma unroll
        for (int n = 0; n < 4; ++n) {
            bf16x8 bh = __builtin_bit_cast(bf16x8, cW[n]);
            bf16x8 bl = __builtin_bit_cast(bf16x8, cW[4 + n]);
            acc[0][n] = __builtin_amdgcn_mfma_f32_16x16x32_bf16(ah0, bh, acc[0][n], 0, 0, 0);
            acc[0][n] = __builtin_amdgcn_mfma_f32_16x16x32_bf16(ah0, bl, acc[0][n], 0, 0, 0);
            acc[0][n] = __builtin_amdgcn_mfma_f32_16x16x32_bf16(al0, bh, acc[0][n], 0, 0, 0);
        }
        if (has1) {
#pragma unroll
            for (int n = 0; n < 4; ++n) {
                bf16x8 bh = __builtin_bit_cast(bf16x8, cW[n]);
                bf16x8 bl = __builtin_bit_cast(bf16x8, cW[4 + n]);
                acc[1][n] = __builtin_amdgcn_mfma_f32_16x16x32_bf16(ah1, bh, acc[1][n], 0, 0, 0);
                acc[1][n] = __builtin_amdgcn_mfma_f32_16x16x32_bf16(ah1, bl, acc[1][n], 0, 0, 0);
                acc[1][n] = __builtin_amdgcn_mfma_f32_16x16x32_bf16(al1, bh, acc[1][n], 0, 0, 0);
            }
        }
        if (s < 12) {
            cAl0 = nAl0; cAh0 = nAh0; cAl1 = nAl1; cAh1 = nAh1;
#pragma unroll
            for (int j = 0; j < 8; ++j) cW[j] = nW[j];
        }
    }

#pragma unroll
    for (int t2 = 0; t2 < 2; ++t2) {
        if (t2 == 1 && !has1) break;
        const int node0 = (t2 ? t1 : t0) * 16 + g * 4;
#pragma unroll
        for (int n = 0; n < 4; ++n) {
            const int col = n * 16 + cl;
            u32x2 pk;
            pk[0] = f2bf(acc[t2][n][0]) | (f2bf(acc[t2][n][1]) << 16);
            pk[1] = f2bf(acc[t2][n][2]) | (f2bf(acc[t2][n][3]) << 16);
            *reinterpret_cast<u32x2*>(&Us[col * UPAD + node0]) = pk;
        }
    }
    __syncthreads();

    // ---- Phase B: Adj @ U (from LDS), single K sweep, 2 live tiles ----
    const float bvs[4] = {bias[cl], bias[16 + cl], bias[32 + cl], bias[48 + cl]};

    f32x4 bacc[2][4];
#pragma unroll
    for (int i = 0; i < 2; ++i)
#pragma unroll
        for (int n = 0; n < 4; ++n) bacc[i][n] = f32x4{0.f, 0.f, 0.f, 0.f};

    for (int k0 = 0; k0 < KP; k0 += 32) {
        const int kk = k0 + g * 8;
        bf16x8 bf[4];
#pragma unroll
        for (int n = 0; n < 4; ++n) {
            const unsigned short* p = &Us[(n * 16 + cl) * UPAD + kk];
            u32x2 lo = *reinterpret_cast<const u32x2*>(p);
            u32x2 hi = *reinterpret_cast<const u32x2*>(p + 4);
            u32x4 w; w[0] = lo[0]; w[1] = lo[1]; w[2] = hi[0]; w[3] = hi[1];
            bf[n] = __builtin_bit_cast(bf16x8, w);
        }
#pragma unroll
        for (int i = 0; i < 2; ++i) {
            const int t = wv + 16 * i;
            if (t < 25) {
                const int row = t * 16 + cl;
                u32x4 ar = *reinterpret_cast<const u32x4*>(&Ad[(size_t)row * KP + kk]);
                bf16x8 af = __builtin_bit_cast(bf16x8, ar);
#pragma unroll
                for (int n = 0; n < 4; ++n)
                    bacc[i][n] = __builtin_amdgcn_mfma_f32_16x16x32_bf16(
                        af, bf[n], bacc[i][n], 0, 0, 0);
            }
        }
    }

#pragma unroll
    for (int i = 0; i < 2; ++i) {
        const int t = wv + 16 * i;
        if (t < 25) {
            float y[4][4];
#pragma unroll
            for (int n = 0; n < 4; ++n)
#pragma unroll
                for (int r = 0; r < 4; ++r) y[n][r] = bacc[i][n][r] + bvs[n];

            float pss[4];
#pragma unroll
            for (int r = 0; r < 4; ++r)
                pss[r] = y[0][r]*y[0][r] + y[1][r]*y[1][r] +
                         y[2][r]*y[2][r] + y[3][r]*y[3][r];
#pragma unroll
            for (int m = 1; m < 16; m <<= 1)
#pragma unroll
                for (int r = 0; r < 4; ++r) pss[r] += __shfl_xor(pss[r], m);

            float rin[4];
#pragma unroll
            for (int r = 0; r < 4; ++r)
                rin[r] = 1.f / fmaxf(sqrtf(pss[r]), 1e-12f);

            float s1[4], s2a[4];
#pragma unroll
            for (int r = 0; r < 4; ++r) { s1[r] = 0.f; s2a[r] = 0.f; }
#pragma unroll
            for (int n = 0; n < 4; ++n)
#pragma unroll
                for (int r = 0; r < 4; ++r) {
                    float z = fmaxf(y[n][r] * rin[r], 0.f);
                    const int row = t * 16 + g * 4 + r;
                    Zout[((size_t)b * Nn + row) * Hh + n * 16 + cl] = z;
                    s1[r] += z;
                    s2a[r] += z * z;
                }
#pragma unroll
            for (int m = 1; m < 16; m <<= 1)
#pragma unroll
                for (int r = 0; r < 4; ++r) {
                    s1[r]  += __shfl_xor(s1[r], m);
                    s2a[r] += __shfl_xor(s2a[r], m);
                }
            if (cl == 0) {
#pragma unroll
                for (int r = 0; r < 4; ++r) {
                    const int row = t * 16 + g * 4 + r;
                    atomicAdd(&ssum[row], s1[r]);
                    atomicAdd(&ssq[row],  s2a[r]);
                }
            }
        }
    }
}

__global__ void finalize_stats(const float* __restrict__ ssum,
                               const float* __restrict__ ssq,
                               float* __restrict__ mean, float* __restrict__ inv) {
    int r = threadIdx.x;
    if (r < Nn) {
        float m = ssum[r] * (1.0f / BH_COUNT);
        float v = ssq[r] * (1.0f / BH_COUNT) - m * m;
        mean[r] = m;
        inv[r]  = rsqrtf(v + 1e-5f);
    }
}

// ---------------------------------------------------------------------------
// Fused layer 2/3 (R11-proven): block = ONE BATCH, 1024 thr = 16 waves.
// Phase A: za = BN-affine(Zin); max(za) -> outmax_za; U = za@W -> LDS
// Phase B: Y = Adj@U + bias; z = normalize(Y);
//   STATS: relu -> Zout + BN stats; else: -> x3 + block col-max -> out3
// ---------------------------------------------------------------------------
template <bool STATS>
__global__ __launch_bounds__(1024) void fusedl(
        const float* __restrict__ Zin,
        const unsigned short* __restrict__ Ad,
        const unsigned short* __restrict__ Wth,   // [64][64] frag layout
        const unsigned short* __restrict__ Wtl,
        const float* __restrict__ mean, const float* __restrict__ inv,
        const float* __restrict__ bias,
        float* __restrict__ Zout,                 // Z (STATS) or x3 (d_out)
        float* __restrict__ ssum, float* __restrict__ ssq,
        float* __restrict__ outmax_za,            // out1 / out2 [B][64]
        float* __restrict__ out3) {               // [B][64] (!STATS)
    __shared__ unsigned short Us[64 * UPAD];      // 53760 B
    __shared__ float sred[16][64];                // 4096 B
    const int b    = blockIdx.x;
    const int tid  = threadIdx.x;
    const int wv   = tid >> 6;                    // 0..15
    const int lane = tid & 63;
    const int cl   = lane & 15;
    const int g    = lane >> 4;

    // zero LDS pad rows (node 400..419)
    for (int i = tid; i < 64 * (UPAD - Nn); i += 1024) {
        int c = i / (UPAD - Nn), k = Nn + i % (UPAD - Nn);
        Us[c * UPAD + k] = 0;
    }

    // ---- Phase A: prefetch both tiles' Z, affine + max + za@W -> LDS ----
    const int t0 = wv;            // < 16 < 25 always
    const int t1 = wv + 16;       // valid iff < 25 (wv < 9)
    const bool has1 = (t1 < 25);

    float za0[16], za1[16];
    {
        const int node = t0 * 16 + cl;
        const float mm = mean[node], iv = inv[node];
#pragma unroll
        for (int s = 0; s < 2; ++s) {
            const float* p = &Zin[((size_t)b * Nn + node) * 64 + s * 32 + g * 8];
            float4 lo = *reinterpret_cast<const float4*>(p);
            float4 hi = *reinterpret_cast<const float4*>(p + 4);
            za0[s * 8 + 0] = (lo.x - mm) * iv;
            za0[s * 8 + 1] = (lo.y - mm) * iv;
            za0[s * 8 + 2] = (lo.z - mm) * iv;
            za0[s * 8 + 3] = (lo.w - mm) * iv;
            za0[s * 8 + 4] = (hi.x - mm) * iv;
            za0[s * 8 + 5] = (hi.y - mm) * iv;
            za0[s * 8 + 6] = (hi.z - mm) * iv;
            za0[s * 8 + 7] = (hi.w - mm) * iv;
        }
    }
    if (has1) {
        const int node = t1 * 16 + cl;
        const float mm = mean[node], iv = inv[node];
#pragma unroll
        for (int s = 0; s < 2; ++s) {
            const float* p = &Zin[((size_t)b * Nn + node) * 64 + s * 32 + g * 8];
            float4 lo = *reinterpret_cast<const float4*>(p);
            float4 hi = *reinterpret_cast<const float4*>(p + 4);
            za1[s * 8 + 0] = (lo.x - mm) * iv;
            za1[s * 8 + 1] = (lo.y - mm) * iv;
            za1[s * 8 + 2] = (lo.z - mm) * iv;
            za1[s * 8 + 3] = (lo.w - mm) * iv;
            za1[s * 8 + 4] = (hi.x - mm) * iv;
            za1[s * 8 + 5] = (hi.y - mm) * iv;
            za1[s * 8 + 6] = (hi.z - mm) * iv;
            za1[s * 8 + 7] = (hi.w - mm) * iv;
        }
    }

    float vmax[16];
#pragma unroll
    for (int j = 0; j < 16; ++j) {
        vmax[j] = za0[j];
        if (has1) vmax[j] = fmaxf(vmax[j], za1[j]);
    }

    auto processA = [&](int t, const float* za) {
        f32x4 acc[4];
#pragma unroll
        for (int n = 0; n < 4; ++n) acc[n] = f32x4{0.f, 0.f, 0.f, 0.f};
#pragma unroll
        for (int s = 0; s < 2; ++s) {
            u32x4 hw, lw;
#pragma unroll
            for (int j = 0; j < 4; ++j) {
                unsigned h0 = f2bf(za[s * 8 + 2 * j]);
                unsigned h1 = f2bf(za[s * 8 + 2 * j + 1]);
                hw[j] = h0 | (h1 << 16);
                lw[j] = f2bf(za[s * 8 + 2 * j] - bf2f(h0)) |
                        (f2bf(za[s * 8 + 2 * j + 1] - bf2f(h1)) << 16);
            }
            bf16x8 ah = __builtin_bit_cast(bf16x8, hw);
            bf16x8 al = __builtin_bit_cast(bf16x8, lw);
            const int kk = s * 32 + g * 8;
#pragma unroll
            for (int n = 0; n < 4; ++n) {
                u32x4 bhw = *reinterpret_cast<const u32x4*>(&Wth[(size_t)(n * 16 + cl) * 64 + kk]);
                u32x4 blw = *reinterpret_cast<const u32x4*>(&Wtl[(size_t)(n * 16 + cl) * 64 + kk]);
                bf16x8 bh = __builtin_bit_cast(bf16x8, bhw);
                bf16x8 bl = __builtin_bit_cast(bf16x8, blw);
                acc[n] = __builtin_amdgcn_mfma_f32_16x16x32_bf16(ah, bh, acc[n], 0, 0, 0);
                acc[n] = __builtin_amdgcn_mfma_f32_16x16x32_bf16(ah, bl, acc[n], 0, 0, 0);
                acc[n] = __builtin_amdgcn_mfma_f32_16x16x32_bf16(al, bh, acc[n], 0, 0, 0);
            }
        }
        const int node0 = t * 16 + g * 4;
#pragma unroll
        for (int n = 0; n < 4; ++n) {
            const int col = n * 16 + cl;
            u32x2 pk;
            pk[0] = f2bf(acc[n][0]) | (f2bf(acc[n][1]) << 16);
            pk[1] = f2bf(acc[n][2]) | (f2bf(acc[n][3]) << 16);
            *reinterpret_cast<u32x2*>(&Us[col * UPAD + node0]) = pk;
        }
    };
    processA(t0, za0);
    if (has1) processA(t1, za1);

    // za-max: reduce over cl (nodes within wave), stash per wave
#pragma unroll
    for (int m = 1; m < 16; m <<= 1)
#pragma unroll
        for (int j = 0; j < 16; ++j)
            vmax[j] = fmaxf(vmax[j], __shfl_xor(vmax[j], m));
    if (cl == 0) {
#pragma unroll
        for (int j = 0; j < 16; ++j) {
            const int h = 32 * (j >> 3) + g * 8 + (j & 7);
            sred[wv][h] = vmax[j];
        }
    }
    __syncthreads();          // covers Us writes + sred
    if (tid < 64) {
        float m = sred[0][tid];
#pragma unroll
        for (int w = 1; w < 16; ++w) m = fmaxf(m, sred[w][tid]);
        outmax_za[b * 64 + tid] = m;
    }

    // ---- Phase B: Adj @ U (from LDS), single K sweep, 2 live tiles ----
    const float bvs[4] = {bias[cl], bias[16 + cl], bias[32 + cl], bias[48 + cl]};
    float pmax[4];
#pragma unroll
    for (int n = 0; n < 4; ++n) pmax[n] = -3.4e38f;

    f32x4 acc[2][4];
#pragma unroll
    for (int i = 0; i < 2; ++i)
#pragma unroll
        for (int n = 0; n < 4; ++n) acc[i][n] = f32x4{0.f, 0.f, 0.f, 0.f};

    for (int k0 = 0; k0 < KP; k0 += 32) {
        const int kk = k0 + g * 8;
        bf16x8 bf[4];
#pragma unroll
        for (int n = 0; n < 4; ++n) {
            const unsigned short* p = &Us[(n * 16 + cl) * UPAD + kk];
            u32x2 lo = *reinterpret_cast<const u32x2*>(p);
            u32x2 hi = *reinterpret_cast<const u32x2*>(p + 4);
            u32x4 w; w[0] = lo[0]; w[1] = lo[1]; w[2] = hi[0]; w[3] = hi[1];
            bf[n] = __builtin_bit_cast(bf16x8, w);
        }
#pragma unroll
        for (int i = 0; i < 2; ++i) {
            const int t = wv + 16 * i;
            if (t < 25) {
                const int row = t * 16 + cl;
                u32x4 ar = *reinterpret_cast<const u32x4*>(&Ad[(size_t)row * KP + kk]);
                bf16x8 af = __builtin_bit_cast(bf16x8, ar);
#pragma unroll
                for (int n = 0; n < 4; ++n)
                    acc[i][n] = __builtin_amdgcn_mfma_f32_16x16x32_bf16(
                        af, bf[n], acc[i][n], 0, 0, 0);
            }
        }
    }

#pragma unroll
    for (int i = 0; i < 2; ++i) {
        const int t = wv + 16 * i;
        if (t < 25) {
            float y[4][4];
#pragma unroll
            for (int n = 0; n < 4; ++n)
#pragma unroll
                for (int r = 0; r < 4; ++r) y[n][r] = acc[i][n][r] + bvs[n];

            float pss[4];
#pragma unroll
            for (int r = 0; r < 4; ++r)
                pss[r] = y[0][r]*y[0][r] + y[1][r]*y[1][r] +
                         y[2][r]*y[2][r] + y[3][r]*y[3][r];
#pragma unroll
            for (int m = 1; m < 16; m <<= 1)
#pragma unroll
                for (int r = 0; r < 4; ++r) pss[r] += __shfl_xor(pss[r], m);

            float rin[4];
#pragma unroll
            for (int r = 0; r < 4; ++r)
                rin[r] = 1.f / fmaxf(sqrtf(pss[r]), 1e-12f);

            float s1[4], s2a[4];
#pragma unroll
            for (int r = 0; r < 4; ++r) { s1[r] = 0.f; s2a[r] = 0.f; }
#pragma unroll
            for (int n = 0; n < 4; ++n)
#pragma unroll
                for (int r = 0; r < 4; ++r) {
                    float z = y[n][r] * rin[r];
                    if (STATS) z = fmaxf(z, 0.f);
                    const int row = t * 16 + g * 4 + r;
                    Zout[((size_t)b * Nn + row) * Hh + n * 16 + cl] = z;
                    if (STATS) { s1[r] += z; s2a[r] += z * z; }
                    else        pmax[n] = fmaxf(pmax[n], z);
                }

            if (STATS) {
#pragma unroll
                for (int m = 1; m < 16; m <<= 1)
#pragma unroll
                    for (int r = 0; r < 4; ++r) {
                        s1[r]  += __shfl_xor(s1[r], m);
                        s2a[r] += __shfl_xor(s2a[r], m);
                    }
                if (cl == 0) {
#pragma unroll
                    for (int r = 0; r < 4; ++r) {
                        const int row = t * 16 + g * 4 + r;
                        atomicAdd(&ssum[row], s1[r]);
                        atomicAdd(&ssq[row],  s2a[r]);
                    }
                }
            }
        }
    }

    if constexpr (!STATS) {
        // block-local column max over all 400 rows -> out3[b][h]
        __syncthreads();
#pragma unroll
        for (int m = 16; m < 64; m <<= 1)
#pragma unroll
            for (int n = 0; n < 4; ++n)
                pmax[n] = fmaxf(pmax[n], __shfl_xor(pmax[n], m));
        if (lane < 16) {
#pragma unroll
            for (int n = 0; n < 4; ++n) sred[wv][n * 16 + cl] = pmax[n];
        }
        __syncthreads();
        if (tid < 64) {
            float m = sred[0][tid];
#pragma unroll
            for (int w = 1; w < 16; ++w) m = fmaxf(m, sred[w][tid]);
            out3[b * 64 + tid] = m;
        }
    }
}

// ---------------------------------------------------------------------------
// FC head: h=[out1|out2|out3] (256x192) -> fc1+relu+bn2 -> fc2+relu+bn2 -> fc3
// ---------------------------------------------------------------------------
__global__ __launch_bounds__(1024) void headk(
        const float* __restrict__ out1, const float* __restrict__ out2,
        const float* __restrict__ out3,
        const float* __restrict__ W1f, const float* __restrict__ b1f,
        const float* __restrict__ W2f, const float* __restrict__ b2f,
        const float* __restrict__ W3f, const float* __restrict__ b3f,
        float* __restrict__ ypred) {
    __shared__ float gA[256][64];     // 64 KB activations
    __shared__ float w1s[192 * 64];   // 48 KB
    __shared__ float w2s[64 * 64];    // 16 KB
    __shared__ float mS[64], iS[64];
    const int t = threadIdx.x;
    const int r = t >> 2, q = t & 3;

    for (int i = t; i < 192 * 64; i += 1024) w1s[i] = W1f[i];
    for (int i = t; i < 64 * 64; i += 1024) w2s[i] = W2f[i];
    __syncthreads();

    float acc[16];
#pragma unroll
    for (int j = 0; j < 16; ++j) acc[j] = b1f[q * 16 + j];
    for (int k = 0; k < 192; ++k) {
        float hv = (k < 64) ? out1[r * 64 + k]
                 : (k < 128) ? out2[r * 64 + (k - 64)]
                             : out3[r * 64 + (k - 128)];
#pragma unroll
        for (int j = 0; j < 16; ++j) acc[j] += hv * w1s[k * 64 + q * 16 + j];
    }
#pragma unroll
    for (int j = 0; j < 16; ++j) gA[r][q * 16 + j] = fmaxf(acc[j], 0.f);
    __syncthreads();

    if (t < 64) {
        float s = 0.f, s2 = 0.f;
        for (int rr = 0; rr < 256; ++rr) { float v = gA[rr][t]; s += v; s2 += v * v; }
        float m = s * (1.f / 256.f);
        float var = s2 * (1.f / 256.f) - m * m;
        mS[t] = m;
        iS[t] = rsqrtf(var + 1e-5f);
    }
    __syncthreads();

#pragma unroll
    for (int j = 0; j < 16; ++j) acc[j] = b2f[q * 16 + j];
#pragma unroll
    for (int k = 0; k < 64; ++k) {
        float gn = (gA[r][k] - mS[k]) * iS[k];
#pragma unroll
        for (int j = 0; j < 16; ++j) acc[j] += gn * w2s[k * 64 + q * 16 + j];
    }
    __syncthreads();
#pragma unroll
    for (int j = 0; j < 16; ++j) gA[r][q * 16 + j] = fmaxf(acc[j], 0.f);
    __syncthreads();

    if (t < 64) {
        float s = 0.f, s2 = 0.f;
        for (int rr = 0; rr < 256; ++rr) { float v = gA[rr][t]; s += v; s2 += v * v; }
        float m = s * (1.f / 256.f);
        float var = s2 * (1.f / 256.f) - m * m;
        mS[t] = m;
        iS[t] = rsqrtf(var + 1e-5f);
    }
    __syncthreads();

    if (q < 2) {
        float a = b3f[q];
#pragma unroll
        for (int k = 0; k < 64; ++k) {
            float gn = (gA[r][k] - mS[k]) * iS[k];
            a += gn * W3f[k * 2 + q];
        }
        ypred[r * 2 + q] = a;
    }
}

// ---------------------------------------------------------------------------
extern "C" void kernel_launch(void* const* d_in, const int* in_sizes, int n_in,
                              void* d_out, int out_size, void* d_ws, size_t ws_size,
                              hipStream_t stream) {
    const float* x    = (const float*)d_in[0];
    const int*   arow = (const int*)d_in[1];
    const int*   acol = (const int*)d_in[2];
    const float* aval = (const float*)d_in[3];
    const float* W1 = (const float*)d_in[4];
    const float* b1 = (const float*)d_in[5];
    const float* W2 = (const float*)d_in[6];
    const float* b2 = (const float*)d_in[7];
    const float* W3 = (const float*)d_in[8];
    const float* b3 = (const float*)d_in[9];
    const float* fc1W = (const float*)d_in[10];
    const float* fc1b = (const float*)d_in[11];
    const float* fc2W = (const float*)d_in[12];
    const float* fc2b = (const float*)d_in[13];
    const float* fc3W = (const float*)d_in[14];
    const float* fc3b = (const float*)d_in[15];

    char* w = (char*)d_ws;
    size_t off = 0;
    float* Adf = (float*)(w + off);            off += (size_t)Nn * KP * 4;
    unsigned short* Adbf = (unsigned short*)(w + off); off += (size_t)Nn * KP * 2;
    unsigned short* T1h = (unsigned short*)(w + off); off += (size_t)64 * 416 * 2;
    unsigned short* T1l = (unsigned short*)(w + off); off += (size_t)64 * 416 * 2;
    unsigned short* T2h = (unsigned short*)(w + off); off += (size_t)64 * 64 * 2;
    unsigned short* T2l = (unsigned short*)(w + off); off += (size_t)64 * 64 * 2;
    unsigned short* T3h = (unsigned short*)(w + off); off += (size_t)64 * 64 * 2;
    unsigned short* T3l = (unsigned short*)(w + off); off += (size_t)64 * 64 * 2;
    float* Z1 = (float*)(w + off);             off += (size_t)Mrows * Hh * 4;
    float* Z2 = (float*)(w + off);             off += (size_t)Mrows * Hh * 4;
    float* stats = (float*)(w + off);          off += 1600 * 4;
    float* ssum1 = stats, *ssq1 = stats + 400, *ssum2 = stats + 800, *ssq2 = stats + 1200;
    float* mean1 = (float*)(w + off); off += 1600;
    float* inv1  = (float*)(w + off); off += 1600;
    float* mean2 = (float*)(w + off); off += 1600;
    float* inv2  = (float*)(w + off); off += 1600;
    float* out1  = (float*)(w + off); off += Bb * Hh * 4;
    float* out2  = (float*)(w + off); off += Bb * Hh * 4;
    float* out3  = (float*)(w + off); off += Bb * Hh * 4;

    float* ypred = (float*)d_out;
    float* x3    = (float*)d_out + 512;

    // Prep: densify adjacency (bf16 [400][416]) + split weights
    initk<<<163, 1024, 0, stream>>>(Adf, stats);
    scatAk<<<(NNZ + 255) / 256, 256, 0, stream>>>(arow, acol, aval, Adf);
    cvtAk<<<(Nn * KP + 1023) / 1024, 1024, 0, stream>>>(Adf, Adbf);
    wprep<<<192, 256, 0, stream>>>(W1, W2, W3, T1h, T1l, T2h, T2l, T3h, T3l);

    // Layer 1 fully fused: x@W1 (LDS) + Adj@U1 + relu + norm + stats
    fused1<<<Bb, 1024, 0, stream>>>(x, T1h, T1l, Adbf, b1, Z1, ssum1, ssq1);
    finalize_stats<<<1, 512, 0, stream>>>(ssum1, ssq1, mean1, inv1);

    // Layer 2 fused: BN1 affine + out1-max + za@W2 (LDS) + Adj@U2 + stats2
    fusedl<true><<<Bb, 1024, 0, stream>>>(Z1, Adbf, T2h, T2l, mean1, inv1, b2,
                                          Z2, ssum2, ssq2, out1, nullptr);
    finalize_stats<<<1, 512, 0, stream>>>(ssum2, ssq2, mean2, inv2);

    // Layer 3 fused: BN2 affine + out2-max + za@W3 (LDS) + Adj@U3 -> x3 + out3
    fusedl<false><<<Bb, 1024, 0, stream>>>(Z2, Adbf, T3h, T3l, mean2, inv2, b3,
                                           x3, nullptr, nullptr, out2, out3);

    // FC head
    headk<<<1, 1024, 0, stream>>>(out1, out2, out3, fc1W, fc1b, fc2W, fc2b,
                                  fc3W, fc3b, ypred);
}

// Round 13
// 305.297 us; speedup vs baseline: 1.0308x; 1.0308x over previous
//
#include <hip/hip_runtime.h>
#include <hip/hip_bf16.h>
#include <math.h>

// Problem constants
#define Bb   256
#define Nn   400
#define FIN  400
#define Hh   64
#define NNZ  16000
#define Mrows (Bb*Nn)          // 102400
#define KP   416               // dense-adj K padded to 13*32 for MFMA
#define UTP  416               // Ut node-dim stride (shorts), layer-1 only
#define UPAD 420               // fused-kernel LDS node stride (shorts)
#define BH_COUNT 16384.0f      // B*H for BN3 stats

typedef unsigned int  u32x2 __attribute__((ext_vector_type(2)));
typedef unsigned int  u32x4 __attribute__((ext_vector_type(4)));
typedef __bf16        bf16x8 __attribute__((ext_vector_type(8)));
typedef float         f32x4 __attribute__((ext_vector_type(4)));

__device__ __forceinline__ unsigned int f2bf(float x) {
    unsigned int u = __builtin_bit_cast(unsigned int, x);
    return (u + 0x7FFFu + ((u >> 16) & 1u)) >> 16;   // RNE
}
__device__ __forceinline__ float bf2f(unsigned int h) {
    unsigned int u = h << 16;
    return __builtin_bit_cast(float, u);
}

// ---------------------------------------------------------------------------
// init: zero dense-A f32 accumulator, BN stats, Ut node-pad (400..415)
// ---------------------------------------------------------------------------
__global__ void initk(float* __restrict__ Adf, float* __restrict__ stats,
                      unsigned short* __restrict__ Ut) {
    int t = blockIdx.x * blockDim.x + threadIdx.x;
    if (t < Nn * KP) Adf[t] = 0.f;
    if (t < 1600) stats[t] = 0.f;   // ssum1, ssq1, ssum2, ssq2 (4 x 400)
    if (t < Bb * Hh * 16) {
        int bh = t >> 4, k = Nn + (t & 15);
        Ut[(size_t)bh * UTP + k] = 0;
    }
}

__global__ void scatAk(const int* __restrict__ rows, const int* __restrict__ cols,
                       const float* __restrict__ vals, float* __restrict__ Adf) {
    int i = blockIdx.x * blockDim.x + threadIdx.x;
    if (i < NNZ) atomicAdd(&Adf[rows[i] * KP + cols[i]], vals[i]);
}

__global__ void cvtAk(const float* __restrict__ Adf, unsigned short* __restrict__ Adbf) {
    int i = blockIdx.x * blockDim.x + threadIdx.x;
    if (i < Nn * KP) Adbf[i] = (unsigned short)f2bf(Adf[i]);
}

// ---------------------------------------------------------------------------
// W prep: split W[KT][64] -> hi/lo bf16 in B-fragment layout [col][KPAD]
// ---------------------------------------------------------------------------
__global__ __launch_bounds__(256) void wprep(
        const float* __restrict__ W1, const float* __restrict__ W2,
        const float* __restrict__ W3,
        unsigned short* __restrict__ T1h, unsigned short* __restrict__ T1l,
        unsigned short* __restrict__ T2h, unsigned short* __restrict__ T2l,
        unsigned short* __restrict__ T3h, unsigned short* __restrict__ T3l) {
    const int w = blockIdx.x >> 6;        // 0,1,2
    const int c = blockIdx.x & 63;
    const float* W = (w == 0) ? W1 : (w == 1) ? W2 : W3;
    const int KT   = (w == 0) ? FIN : Hh;
    const int KPAD = (w == 0) ? 416 : 64;
    unsigned short* Th = (w == 0) ? T1h : (w == 1) ? T2h : T3h;
    unsigned short* Tl = (w == 0) ? T1l : (w == 1) ? T2l : T3l;

    for (int k = threadIdx.x; k < KPAD; k += 256) {
        float v = (k < KT) ? W[k * 64 + c] : 0.f;
        unsigned int hb = f2bf(v);
        Th[c * KPAD + k] = (unsigned short)hb;
        Tl[c * KPAD + k] = (unsigned short)f2bf(v - bf2f(hb));
    }
}

// ---------------------------------------------------------------------------
// Layer-1 GEMM (split precision, LDS-free, pipelined) — R8-proven:
//   Ut = x[M,400](f32) @ W1[400,64]  -> bf16, transposed per batch
// ---------------------------------------------------------------------------
__global__ __launch_bounds__(256) void xg400(
        const float* __restrict__ A,
        const unsigned short* __restrict__ Wth,
        const unsigned short* __restrict__ Wtl,
        unsigned short* __restrict__ Ut) {
    const int tid  = threadIdx.x;
    const int wv   = tid >> 6;
    const int lane = tid & 63;
    const int cl   = lane & 15;
    const int g    = lane >> 4;
    const int m0   = blockIdx.x * 128;
    const int rowA = m0 + wv * 32 + cl;
    const int rowB = rowA + 16;

    f32x4 acc[2][4];
#pragma unroll
    for (int t2 = 0; t2 < 2; ++t2)
#pragma unroll
        for (int n = 0; n < 4; ++n) acc[t2][n] = f32x4{0.f, 0.f, 0.f, 0.f};

    auto loadA = [&](int s, float4& l0, float4& h0, float4& l1, float4& h1) {
        int kk = s * 32 + g * 8;
        int kc = kk > 392 ? 392 : kk;                 // clamp (W pad is zero)
        const float* p = &A[(size_t)rowA * FIN + kc];
        l0 = *reinterpret_cast<const float4*>(p);
        h0 = *reinterpret_cast<const float4*>(p + 4);
        const float* q = &A[(size_t)rowB * FIN + kc];
        l1 = *reinterpret_cast<const float4*>(q);
        h1 = *reinterpret_cast<const float4*>(q + 4);
    };
    auto loadW = [&](int s, u32x4* dst) {
        int kk = s * 32 + g * 8;
#pragma unroll
        for (int n = 0; n < 4; ++n) {
            dst[n]     = *reinterpret_cast<const u32x4*>(&Wth[(size_t)(n * 16 + cl) * 416 + kk]);
            dst[4 + n] = *reinterpret_cast<const u32x4*>(&Wtl[(size_t)(n * 16 + cl) * 416 + kk]);
        }
    };
    auto split = [&](const float4& lo, const float4& hi, bf16x8& ah, bf16x8& al) {
        float v0 = lo.x, v1 = lo.y, v2 = lo.z, v3 = lo.w;
        float v4 = hi.x, v5 = hi.y, v6 = hi.z, v7 = hi.w;
        unsigned h0, h1;
        u32x4 hw, lw;
        h0 = f2bf(v0); h1 = f2bf(v1);
        hw[0] = h0 | (h1 << 16);
        lw[0] = f2bf(v0 - bf2f(h0)) | (f2bf(v1 - bf2f(h1)) << 16);
        h0 = f2bf(v2); h1 = f2bf(v3);
        hw[1] = h0 | (h1 << 16);
        lw[1] = f2bf(v2 - bf2f(h0)) | (f2bf(v3 - bf2f(h1)) << 16);
        h0 = f2bf(v4); h1 = f2bf(v5);
        hw[2] = h0 | (h1 << 16);
        lw[2] = f2bf(v4 - bf2f(h0)) | (f2bf(v5 - bf2f(h1)) << 16);
        h0 = f2bf(v6); h1 = f2bf(v7);
        hw[3] = h0 | (h1 << 16);
        lw[3] = f2bf(v6 - bf2f(h0)) | (f2bf(v7 - bf2f(h1)) << 16);
        ah = __builtin_bit_cast(bf16x8, hw);
        al = __builtin_bit_cast(bf16x8, lw);
    };

    float4 cAl0, cAh0, cAl1, cAh1, nAl0, nAh0, nAl1, nAh1;
    u32x4  cW[8], nW[8];
    loadA(0, cAl0, cAh0, cAl1, cAh1);
    loadW(0, cW);

    for (int s = 0; s < 13; ++s) {
        if (s < 12) {
            loadA(s + 1, nAl0, nAh0, nAl1, nAh1);
            loadW(s + 1, nW);
        }
        bf16x8 ah0, al0, ah1, al1;
        split(cAl0, cAh0, ah0, al0);
        split(cAl1, cAh1, ah1, al1);
#pragma unroll
        for (int n = 0; n < 4; ++n) {
            bf16x8 bh = __builtin_bit_cast(bf16x8, cW[n]);
            bf16x8 bl = __builtin_bit_cast(bf16x8, cW[4 + n]);
            acc[0][n] = __builtin_amdgcn_mfma_f32_16x16x32_bf16(ah0, bh, acc[0][n], 0, 0, 0);
            acc[0][n] = __builtin_amdgcn_mfma_f32_16x16x32_bf16(ah0, bl, acc[0][n], 0, 0, 0);
            acc[0][n] = __builtin_amdgcn_mfma_f32_16x16x32_bf16(al0, bh, acc[0][n], 0, 0, 0);
            acc[1][n] = __builtin_amdgcn_mfma_f32_16x16x32_bf16(ah1, bh, acc[1][n], 0, 0, 0);
            acc[1][n] = __builtin_amdgcn_mfma_f32_16x16x32_bf16(ah1, bl, acc[1][n], 0, 0, 0);
            acc[1][n] = __builtin_amdgcn_mfma_f32_16x16x32_bf16(al1, bh, acc[1][n], 0, 0, 0);
        }
        if (s < 12) {
            cAl0 = nAl0; cAh0 = nAh0; cAl1 = nAl1; cAh1 = nAh1;
#pragma unroll
            for (int j = 0; j < 8; ++j) cW[j] = nW[j];
        }
    }

#pragma unroll
    for (int t2 = 0; t2 < 2; ++t2) {
        const int row0  = m0 + wv * 32 + t2 * 16 + g * 4;
        const int b     = row0 / Nn;
        const int node0 = row0 - b * Nn;
#pragma unroll
        for (int n = 0; n < 4; ++n) {
            const int col = n * 16 + cl;
            u32x2 pk;
            pk[0] = f2bf(acc[t2][n][0]) | (f2bf(acc[t2][n][1]) << 16);
            pk[1] = f2bf(acc[t2][n][2]) | (f2bf(acc[t2][n][3]) << 16);
            *reinterpret_cast<u32x2*>(&Ut[((size_t)b * 64 + col) * UTP + node0]) = pk;
        }
    }
}

// ---------------------------------------------------------------------------
// Layer-1 aggregation (R9-proven): Z[b] = relu(normalize(Adj@U[b] + b1)),
// + BN stats. 4 blocks per batch, reads Ut from global.
// ---------------------------------------------------------------------------
__global__ __launch_bounds__(256) void aggmm(
        const unsigned short* __restrict__ Ad,
        const unsigned short* __restrict__ Ut,
        const float* __restrict__ bias,
        float* __restrict__ Zout,
        float* __restrict__ ssum, float* __restrict__ ssq) {
    const int b    = blockIdx.x >> 2;
    const int q    = blockIdx.x & 3;
    const int tid  = threadIdx.x;
    const int lane = tid & 63;
    const int wv   = tid >> 6;
    const int cl   = lane & 15;
    const int g    = lane >> 4;
    const unsigned short* __restrict__ Ub = Ut + (size_t)b * 64 * UTP;

    f32x4 acc[2][4];
#pragma unroll
    for (int i = 0; i < 2; ++i)
#pragma unroll
        for (int n = 0; n < 4; ++n) acc[i][n] = f32x4{0.f, 0.f, 0.f, 0.f};

    for (int k0 = 0; k0 < KP; k0 += 32) {
        const int kk = k0 + g * 8;
        bf16x8 bf[4];
#pragma unroll
        for (int n = 0; n < 4; ++n) {
            u32x4 w = *reinterpret_cast<const u32x4*>(&Ub[(size_t)(n * 16 + cl) * UTP + kk]);
            bf[n] = __builtin_bit_cast(bf16x8, w);
        }
#pragma unroll
        for (int i = 0; i < 2; ++i) {
            const int t = q + 4 * wv + 16 * i;
            if (t < 25) {
                const int row = t * 16 + cl;
                u32x4 ar = *reinterpret_cast<const u32x4*>(&Ad[(size_t)row * KP + kk]);
                bf16x8 af = __builtin_bit_cast(bf16x8, ar);
#pragma unroll
                for (int n = 0; n < 4; ++n)
                    acc[i][n] = __builtin_amdgcn_mfma_f32_16x16x32_bf16(
                        af, bf[n], acc[i][n], 0, 0, 0);
            }
        }
    }

    float bv[4];
#pragma unroll
    for (int n = 0; n < 4; ++n) bv[n] = bias[n * 16 + cl];

#pragma unroll
    for (int i = 0; i < 2; ++i) {
        const int t = q + 4 * wv + 16 * i;
        if (t < 25) {
            float y[4][4];
#pragma unroll
            for (int n = 0; n < 4; ++n)
#pragma unroll
                for (int r = 0; r < 4; ++r) y[n][r] = acc[i][n][r] + bv[n];

            float pss[4];
#pragma unroll
            for (int r = 0; r < 4; ++r)
                pss[r] = y[0][r]*y[0][r] + y[1][r]*y[1][r] +
                         y[2][r]*y[2][r] + y[3][r]*y[3][r];
#pragma unroll
            for (int m = 1; m < 16; m <<= 1)
#pragma unroll
                for (int r = 0; r < 4; ++r) pss[r] += __shfl_xor(pss[r], m);

            float rin[4];
#pragma unroll
            for (int r = 0; r < 4; ++r)
                rin[r] = 1.f / fmaxf(sqrtf(pss[r]), 1e-12f);

            float s1[4], s2[4];
#pragma unroll
            for (int r = 0; r < 4; ++r) { s1[r] = 0.f; s2[r] = 0.f; }
#pragma unroll
            for (int n = 0; n < 4; ++n)
#pragma unroll
                for (int r = 0; r < 4; ++r) {
                    float z = fmaxf(y[n][r] * rin[r], 0.f);
                    const int row = t * 16 + g * 4 + r;
                    Zout[((size_t)b * Nn + row) * Hh + n * 16 + cl] = z;
                    s1[r] += z;
                    s2[r] += z * z;
                }
#pragma unroll
            for (int m = 1; m < 16; m <<= 1)
#pragma unroll
                for (int r = 0; r < 4; ++r) {
                    s1[r] += __shfl_xor(s1[r], m);
                    s2[r] += __shfl_xor(s2[r], m);
                }
            if (cl == 0) {
#pragma unroll
                for (int r = 0; r < 4; ++r) {
                    const int row = t * 16 + g * 4 + r;
                    atomicAdd(&ssum[row], s1[r]);
                    atomicAdd(&ssq[row],  s2[r]);
                }
            }
        }
    }
}

__global__ void finalize_stats(const float* __restrict__ ssum,
                               const float* __restrict__ ssq,
                               float* __restrict__ mean, float* __restrict__ inv) {
    int r = threadIdx.x;
    if (r < Nn) {
        float m = ssum[r] * (1.0f / BH_COUNT);
        float v = ssq[r] * (1.0f / BH_COUNT) - m * m;
        mean[r] = m;
        inv[r]  = rsqrtf(v + 1e-5f);
    }
}

// ---------------------------------------------------------------------------
// Fused layer 2/3 (R11-proven): block = ONE BATCH, 1024 thr = 16 waves.
// Phase A: za = BN-affine(Zin); max(za) -> outmax_za; U = za@W -> LDS
// Phase B: Y = Adj@U + bias; z = normalize(Y);
//   STATS: relu -> Zout + BN stats; else: -> x3 + block col-max -> out3
// ---------------------------------------------------------------------------
template <bool STATS>
__global__ __launch_bounds__(1024) void fusedl(
        const float* __restrict__ Zin,
        const unsigned short* __restrict__ Ad,
        const unsigned short* __restrict__ Wth,   // [64][64] frag layout
        const unsigned short* __restrict__ Wtl,
        const float* __restrict__ mean, const float* __restrict__ inv,
        const float* __restrict__ bias,
        float* __restrict__ Zout,                 // Z (STATS) or x3 (d_out)
        float* __restrict__ ssum, float* __restrict__ ssq,
        float* __restrict__ outmax_za,            // out1 / out2 [B][64]
        float* __restrict__ out3) {               // [B][64] (!STATS)
    __shared__ unsigned short Us[64 * UPAD];      // 53760 B
    __shared__ float sred[16][64];                // 4096 B
    const int b    = blockIdx.x;
    const int tid  = threadIdx.x;
    const int wv   = tid >> 6;                    // 0..15
    const int lane = tid & 63;
    const int cl   = lane & 15;
    const int g    = lane >> 4;

    // zero LDS pad rows (node 400..419)
    for (int i = tid; i < 64 * (UPAD - Nn); i += 1024) {
        int c = i / (UPAD - Nn), k = Nn + i % (UPAD - Nn);
        Us[c * UPAD + k] = 0;
    }

    // ---- Phase A: prefetch both tiles' Z, affine + max + za@W -> LDS ----
    const int t0 = wv;            // < 16 < 25 always
    const int t1 = wv + 16;       // valid iff < 25 (wv < 9)
    const bool has1 = (t1 < 25);

    float za0[16], za1[16];
    {
        const int node = t0 * 16 + cl;
        const float mm = mean[node], iv = inv[node];
#pragma unroll
        for (int s = 0; s < 2; ++s) {
            const float* p = &Zin[((size_t)b * Nn + node) * 64 + s * 32 + g * 8];
            float4 lo = *reinterpret_cast<const float4*>(p);
            float4 hi = *reinterpret_cast<const float4*>(p + 4);
            za0[s * 8 + 0] = (lo.x - mm) * iv;
            za0[s * 8 + 1] = (lo.y - mm) * iv;
            za0[s * 8 + 2] = (lo.z - mm) * iv;
            za0[s * 8 + 3] = (lo.w - mm) * iv;
            za0[s * 8 + 4] = (hi.x - mm) * iv;
            za0[s * 8 + 5] = (hi.y - mm) * iv;
            za0[s * 8 + 6] = (hi.z - mm) * iv;
            za0[s * 8 + 7] = (hi.w - mm) * iv;
        }
    }
    if (has1) {
        const int node = t1 * 16 + cl;
        const float mm = mean[node], iv = inv[node];
#pragma unroll
        for (int s = 0; s < 2; ++s) {
            const float* p = &Zin[((size_t)b * Nn + node) * 64 + s * 32 + g * 8];
            float4 lo = *reinterpret_cast<const float4*>(p);
            float4 hi = *reinterpret_cast<const float4*>(p + 4);
            za1[s * 8 + 0] = (lo.x - mm) * iv;
            za1[s * 8 + 1] = (lo.y - mm) * iv;
            za1[s * 8 + 2] = (lo.z - mm) * iv;
            za1[s * 8 + 3] = (lo.w - mm) * iv;
            za1[s * 8 + 4] = (hi.x - mm) * iv;
            za1[s * 8 + 5] = (hi.y - mm) * iv;
            za1[s * 8 + 6] = (hi.z - mm) * iv;
            za1[s * 8 + 7] = (hi.w - mm) * iv;
        }
    }

    float vmax[16];
#pragma unroll
    for (int j = 0; j < 16; ++j) {
        vmax[j] = za0[j];
        if (has1) vmax[j] = fmaxf(vmax[j], za1[j]);
    }

    auto processA = [&](int t, const float* za) {
        f32x4 acc[4];
#pragma unroll
        for (int n = 0; n < 4; ++n) acc[n] = f32x4{0.f, 0.f, 0.f, 0.f};
#pragma unroll
        for (int s = 0; s < 2; ++s) {
            u32x4 hw, lw;
#pragma unroll
            for (int j = 0; j < 4; ++j) {
                unsigned h0 = f2bf(za[s * 8 + 2 * j]);
                unsigned h1 = f2bf(za[s * 8 + 2 * j + 1]);
                hw[j] = h0 | (h1 << 16);
                lw[j] = f2bf(za[s * 8 + 2 * j] - bf2f(h0)) |
                        (f2bf(za[s * 8 + 2 * j + 1] - bf2f(h1)) << 16);
            }
            bf16x8 ah = __builtin_bit_cast(bf16x8, hw);
            bf16x8 al = __builtin_bit_cast(bf16x8, lw);
            const int kk = s * 32 + g * 8;
#pragma unroll
            for (int n = 0; n < 4; ++n) {
                u32x4 bhw = *reinterpret_cast<const u32x4*>(&Wth[(size_t)(n * 16 + cl) * 64 + kk]);
                u32x4 blw = *reinterpret_cast<const u32x4*>(&Wtl[(size_t)(n * 16 + cl) * 64 + kk]);
                bf16x8 bh = __builtin_bit_cast(bf16x8, bhw);
                bf16x8 bl = __builtin_bit_cast(bf16x8, blw);
                acc[n] = __builtin_amdgcn_mfma_f32_16x16x32_bf16(ah, bh, acc[n], 0, 0, 0);
                acc[n] = __builtin_amdgcn_mfma_f32_16x16x32_bf16(ah, bl, acc[n], 0, 0, 0);
                acc[n] = __builtin_amdgcn_mfma_f32_16x16x32_bf16(al, bh, acc[n], 0, 0, 0);
            }
        }
        const int node0 = t * 16 + g * 4;
#pragma unroll
        for (int n = 0; n < 4; ++n) {
            const int col = n * 16 + cl;
            u32x2 pk;
            pk[0] = f2bf(acc[n][0]) | (f2bf(acc[n][1]) << 16);
            pk[1] = f2bf(acc[n][2]) | (f2bf(acc[n][3]) << 16);
            *reinterpret_cast<u32x2*>(&Us[col * UPAD + node0]) = pk;
        }
    };
    processA(t0, za0);
    if (has1) processA(t1, za1);

    // za-max: reduce over cl (nodes within wave), stash per wave
#pragma unroll
    for (int m = 1; m < 16; m <<= 1)
#pragma unroll
        for (int j = 0; j < 16; ++j)
            vmax[j] = fmaxf(vmax[j], __shfl_xor(vmax[j], m));
    if (cl == 0) {
#pragma unroll
        for (int j = 0; j < 16; ++j) {
            const int h = 32 * (j >> 3) + g * 8 + (j & 7);
            sred[wv][h] = vmax[j];
        }
    }
    __syncthreads();          // covers Us writes + sred
    if (tid < 64) {
        float m = sred[0][tid];
#pragma unroll
        for (int w = 1; w < 16; ++w) m = fmaxf(m, sred[w][tid]);
        outmax_za[b * 64 + tid] = m;
    }

    // ---- Phase B: Adj @ U (from LDS), single K sweep, 2 live tiles ----
    const float bvs[4] = {bias[cl], bias[16 + cl], bias[32 + cl], bias[48 + cl]};
    float pmax[4];
#pragma unroll
    for (int n = 0; n < 4; ++n) pmax[n] = -3.4e38f;

    f32x4 acc[2][4];
#pragma unroll
    for (int i = 0; i < 2; ++i)
#pragma unroll
        for (int n = 0; n < 4; ++n) acc[i][n] = f32x4{0.f, 0.f, 0.f, 0.f};

    for (int k0 = 0; k0 < KP; k0 += 32) {
        const int kk = k0 + g * 8;
        bf16x8 bf[4];
#pragma unroll
        for (int n = 0; n < 4; ++n) {
            const unsigned short* p = &Us[(n * 16 + cl) * UPAD + kk];
            u32x2 lo = *reinterpret_cast<const u32x2*>(p);
            u32x2 hi = *reinterpret_cast<const u32x2*>(p + 4);
            u32x4 w; w[0] = lo[0]; w[1] = lo[1]; w[2] = hi[0]; w[3] = hi[1];
            bf[n] = __builtin_bit_cast(bf16x8, w);
        }
#pragma unroll
        for (int i = 0; i < 2; ++i) {
            const int t = wv + 16 * i;
            if (t < 25) {
                const int row = t * 16 + cl;
                u32x4 ar = *reinterpret_cast<const u32x4*>(&Ad[(size_t)row * KP + kk]);
                bf16x8 af = __builtin_bit_cast(bf16x8, ar);
#pragma unroll
                for (int n = 0; n < 4; ++n)
                    acc[i][n] = __builtin_amdgcn_mfma_f32_16x16x32_bf16(
                        af, bf[n], acc[i][n], 0, 0, 0);
            }
        }
    }

#pragma unroll
    for (int i = 0; i < 2; ++i) {
        const int t = wv + 16 * i;
        if (t < 25) {
            float y[4][4];
#pragma unroll
            for (int n = 0; n < 4; ++n)
#pragma unroll
                for (int r = 0; r < 4; ++r) y[n][r] = acc[i][n][r] + bvs[n];

            float pss[4];
#pragma unroll
            for (int r = 0; r < 4; ++r)
                pss[r] = y[0][r]*y[0][r] + y[1][r]*y[1][r] +
                         y[2][r]*y[2][r] + y[3][r]*y[3][r];
#pragma unroll
            for (int m = 1; m < 16; m <<= 1)
#pragma unroll
                for (int r = 0; r < 4; ++r) pss[r] += __shfl_xor(pss[r], m);

            float rin[4];
#pragma unroll
            for (int r = 0; r < 4; ++r)
                rin[r] = 1.f / fmaxf(sqrtf(pss[r]), 1e-12f);

            float s1[4], s2a[4];
#pragma unroll
            for (int r = 0; r < 4; ++r) { s1[r] = 0.f; s2a[r] = 0.f; }
#pragma unroll
            for (int n = 0; n < 4; ++n)
#pragma unroll
                for (int r = 0; r < 4; ++r) {
                    float z = y[n][r] * rin[r];
                    if (STATS) z = fmaxf(z, 0.f);
                    const int row = t * 16 + g * 4 + r;
                    Zout[((size_t)b * Nn + row) * Hh + n * 16 + cl] = z;
                    if (STATS) { s1[r] += z; s2a[r] += z * z; }
                    else        pmax[n] = fmaxf(pmax[n], z);
                }

            if (STATS) {
#pragma unroll
                for (int m = 1; m < 16; m <<= 1)
#pragma unroll
                    for (int r = 0; r < 4; ++r) {
                        s1[r]  += __shfl_xor(s1[r], m);
                        s2a[r] += __shfl_xor(s2a[r], m);
                    }
                if (cl == 0) {
#pragma unroll
                    for (int r = 0; r < 4; ++r) {
                        const int row = t * 16 + g * 4 + r;
                        atomicAdd(&ssum[row], s1[r]);
                        atomicAdd(&ssq[row],  s2a[r]);
                    }
                }
            }
        }
    }

    if constexpr (!STATS) {
        // block-local column max over all 400 rows -> out3[b][h]
        __syncthreads();
#pragma unroll
        for (int m = 16; m < 64; m <<= 1)
#pragma unroll
            for (int n = 0; n < 4; ++n)
                pmax[n] = fmaxf(pmax[n], __shfl_xor(pmax[n], m));
        if (lane < 16) {
#pragma unroll
            for (int n = 0; n < 4; ++n) sred[wv][n * 16 + cl] = pmax[n];
        }
        __syncthreads();
        if (tid < 64) {
            float m = sred[0][tid];
#pragma unroll
            for (int w = 1; w < 16; ++w) m = fmaxf(m, sred[w][tid]);
            out3[b * 64 + tid] = m;
        }
    }
}

// ---------------------------------------------------------------------------
// FC head: h=[out1|out2|out3] (256x192) -> fc1+relu+bn2 -> fc2+relu+bn2 -> fc3
// ---------------------------------------------------------------------------
__global__ __launch_bounds__(1024) void headk(
        const float* __restrict__ out1, const float* __restrict__ out2,
        const float* __restrict__ out3,
        const float* __restrict__ W1f, const float* __restrict__ b1f,
        const float* __restrict__ W2f, const float* __restrict__ b2f,
        const float* __restrict__ W3f, const float* __restrict__ b3f,
        float* __restrict__ ypred) {
    __shared__ float gA[256][64];     // 64 KB activations
    __shared__ float w1s[192 * 64];   // 48 KB
    __shared__ float w2s[64 * 64];    // 16 KB
    __shared__ float mS[64], iS[64];
    const int t = threadIdx.x;
    const int r = t >> 2, q = t & 3;

    for (int i = t; i < 192 * 64; i += 1024) w1s[i] = W1f[i];
    for (int i = t; i < 64 * 64; i += 1024) w2s[i] = W2f[i];
    __syncthreads();

    float acc[16];
#pragma unroll
    for (int j = 0; j < 16; ++j) acc[j] = b1f[q * 16 + j];
    for (int k = 0; k < 192; ++k) {
        float hv = (k < 64) ? out1[r * 64 + k]
                 : (k < 128) ? out2[r * 64 + (k - 64)]
                             : out3[r * 64 + (k - 128)];
#pragma unroll
        for (int j = 0; j < 16; ++j) acc[j] += hv * w1s[k * 64 + q * 16 + j];
    }
#pragma unroll
    for (int j = 0; j < 16; ++j) gA[r][q * 16 + j] = fmaxf(acc[j], 0.f);
    __syncthreads();

    if (t < 64) {
        float s = 0.f, s2 = 0.f;
        for (int rr = 0; rr < 256; ++rr) { float v = gA[rr][t]; s += v; s2 += v * v; }
        float m = s * (1.f / 256.f);
        float var = s2 * (1.f / 256.f) - m * m;
        mS[t] = m;
        iS[t] = rsqrtf(var + 1e-5f);
    }
    __syncthreads();

#pragma unroll
    for (int j = 0; j < 16; ++j) acc[j] = b2f[q * 16 + j];
#pragma unroll
    for (int k = 0; k < 64; ++k) {
        float gn = (gA[r][k] - mS[k]) * iS[k];
#pragma unroll
        for (int j = 0; j < 16; ++j) acc[j] += gn * w2s[k * 64 + q * 16 + j];
    }
    __syncthreads();
#pragma unroll
    for (int j = 0; j < 16; ++j) gA[r][q * 16 + j] = fmaxf(acc[j], 0.f);
    __syncthreads();

    if (t < 64) {
        float s = 0.f, s2 = 0.f;
        for (int rr = 0; rr < 256; ++rr) { float v = gA[rr][t]; s += v; s2 += v * v; }
        float m = s * (1.f / 256.f);
        float var = s2 * (1.f / 256.f) - m * m;
        mS[t] = m;
        iS[t] = rsqrtf(var + 1e-5f);
    }
    __syncthreads();

    if (q < 2) {
        float a = b3f[q];
#pragma unroll
        for (int k = 0; k < 64; ++k) {
            float gn = (gA[r][k] - mS[k]) * iS[k];
            a += gn * W3f[k * 2 + q];
        }
        ypred[r * 2 + q] = a;
    }
}

// ---------------------------------------------------------------------------
extern "C" void kernel_launch(void* const* d_in, const int* in_sizes, int n_in,
                              void* d_out, int out_size, void* d_ws, size_t ws_size,
                              hipStream_t stream) {
    const float* x    = (const float*)d_in[0];
    const int*   arow = (const int*)d_in[1];
    const int*   acol = (const int*)d_in[2];
    const float* aval = (const float*)d_in[3];
    const float* W1 = (const float*)d_in[4];
    const float* b1 = (const float*)d_in[5];
    const float* W2 = (const float*)d_in[6];
    const float* b2 = (const float*)d_in[7];
    const float* W3 = (const float*)d_in[8];
    const float* b3 = (const float*)d_in[9];
    const float* fc1W = (const float*)d_in[10];
    const float* fc1b = (const float*)d_in[11];
    const float* fc2W = (const float*)d_in[12];
    const float* fc2b = (const float*)d_in[13];
    const float* fc3W = (const float*)d_in[14];
    const float* fc3b = (const float*)d_in[15];

    char* w = (char*)d_ws;
    size_t off = 0;
    float* Adf = (float*)(w + off);            off += (size_t)Nn * KP * 4;
    unsigned short* Adbf = (unsigned short*)(w + off); off += (size_t)Nn * KP * 2;
    unsigned short* T1h = (unsigned short*)(w + off); off += (size_t)64 * 416 * 2;
    unsigned short* T1l = (unsigned short*)(w + off); off += (size_t)64 * 416 * 2;
    unsigned short* T2h = (unsigned short*)(w + off); off += (size_t)64 * 64 * 2;
    unsigned short* T2l = (unsigned short*)(w + off); off += (size_t)64 * 64 * 2;
    unsigned short* T3h = (unsigned short*)(w + off); off += (size_t)64 * 64 * 2;
    unsigned short* T3l = (unsigned short*)(w + off); off += (size_t)64 * 64 * 2;
    unsigned short* Ut = (unsigned short*)(w + off); off += (size_t)Bb * 64 * UTP * 2;
    float* Z1 = (float*)(w + off);             off += (size_t)Mrows * Hh * 4;
    float* Z2 = (float*)(w + off);             off += (size_t)Mrows * Hh * 4;
    float* stats = (float*)(w + off);          off += 1600 * 4;
    float* ssum1 = stats, *ssq1 = stats + 400, *ssum2 = stats + 800, *ssq2 = stats + 1200;
    float* mean1 = (float*)(w + off); off += 1600;
    float* inv1  = (float*)(w + off); off += 1600;
    float* mean2 = (float*)(w + off); off += 1600;
    float* inv2  = (float*)(w + off); off += 1600;
    float* out1  = (float*)(w + off); off += Bb * Hh * 4;
    float* out2  = (float*)(w + off); off += Bb * Hh * 4;
    float* out3  = (float*)(w + off); off += Bb * Hh * 4;

    float* ypred = (float*)d_out;
    float* x3    = (float*)d_out + 512;

    // Prep: densify adjacency (bf16 [400][416]) + split weights
    initk<<<384, 1024, 0, stream>>>(Adf, stats, Ut);
    scatAk<<<(NNZ + 255) / 256, 256, 0, stream>>>(arow, acol, aval, Adf);
    cvtAk<<<(Nn * KP + 1023) / 1024, 1024, 0, stream>>>(Adf, Adbf);
    wprep<<<192, 256, 0, stream>>>(W1, W2, W3, T1h, T1l, T2h, T2l, T3h, T3l);

    // Layer 1
    xg400<<<Mrows / 128, 256, 0, stream>>>(x, T1h, T1l, Ut);
    aggmm<<<Bb * 4, 256, 0, stream>>>(Adbf, Ut, b1, Z1, ssum1, ssq1);
    finalize_stats<<<1, 512, 0, stream>>>(ssum1, ssq1, mean1, inv1);

    // Layer 2 fused: BN1 affine + out1-max + za@W2 (LDS) + Adj@U2 + stats2
    fusedl<true><<<Bb, 1024, 0, stream>>>(Z1, Adbf, T2h, T2l, mean1, inv1, b2,
                                          Z2, ssum2, ssq2, out1, nullptr);
    finalize_stats<<<1, 512, 0, stream>>>(ssum2, ssq2, mean2, inv2);

    // Layer 3 fused: BN2 affine + out2-max + za@W3 (LDS) + Adj@U3 -> x3 + out3
    fusedl<false><<<Bb, 1024, 0, stream>>>(Z2, Adbf, T3h, T3l, mean2, inv2, b3,
                                           x3, nullptr, nullptr, out2, out3);

    // FC head
    headk<<<1, 1024, 0, stream>>>(out1, out2, out3, fc1W, fc1b, fc2W, fc2b,
                                  fc3W, fc3b, ypred);
}